// Round 2
// baseline (652.611 us; speedup 1.0000x reference)
//
#include <hip/hip_runtime.h>
#include <stdint.h>
#include <math.h>

// ---------------- types ----------------
typedef __attribute__((ext_vector_type(4))) float f32x4;
typedef __attribute__((ext_vector_type(8))) short s16x8;   // 8 x bf16 (4 VGPRs)
typedef __attribute__((ext_vector_type(4))) unsigned short u16x4;

__device__ __forceinline__ unsigned short f2b(float x) {
    union { float f; uint32_t u; } v; v.f = x;
    uint32_t r = v.u + 0x7FFFu + ((v.u >> 16) & 1u);   // round-to-nearest-even
    return (unsigned short)(r >> 16);
}

__device__ __forceinline__ void gload16(const unsigned short* g, unsigned short* l) {
    __builtin_amdgcn_global_load_lds(
        (const __attribute__((address_space(1))) unsigned int*)(const void*)g,
        (__attribute__((address_space(3))) unsigned int*)(void*)l,
        16, 0, 0);
}

// swizzled LDS reads: row-major tile, rowstride 128B (rd7) / 256B (rd8),
// byte ^= (row&7)<<4 spreads the 16-lane row-column slice across banks.
__device__ __forceinline__ s16x8 rd7(const unsigned short* t, int row, int cb) {
    return *(const s16x8*)((const char*)t + (row << 7) + (cb ^ ((row & 7) << 4)));
}
__device__ __forceinline__ s16x8 rd8(const unsigned short* t, int row, int cb) {
    return *(const s16x8*)((const char*)t + (row << 8) + (cb ^ ((row & 7) << 4)));
}

// ---------------- fp32 -> bf16 cast ----------------
__global__ __launch_bounds__(256) void cast_kernel(const float* __restrict__ in,
                                                   unsigned short* __restrict__ out,
                                                   int n4) {
    int i = blockIdx.x * 256 + threadIdx.x;
    if (i >= n4) return;
    f32x4 v = ((const f32x4*)in)[i];
    u16x4 o;
    #pragma unroll
    for (int j = 0; j < 4; ++j) o[j] = f2b(v[j]);
    ((u16x4*)out)[i] = o;
}

// ---------------- LayerNorm (C=1024), fp32 in -> bf16 out ----------------
__global__ __launch_bounds__(256) void ln_kernel(const float* __restrict__ x,
                                                 const float* __restrict__ w,
                                                 const float* __restrict__ b,
                                                 unsigned short* __restrict__ out) {
    const long row = blockIdx.x;
    const int tid = threadIdx.x;
    f32x4 v = *(const f32x4*)(x + row * 1024 + tid * 4);
    float s  = v[0] + v[1] + v[2] + v[3];
    float sq = v[0]*v[0] + v[1]*v[1] + v[2]*v[2] + v[3]*v[3];
    #pragma unroll
    for (int off = 32; off; off >>= 1) {
        s  += __shfl_xor(s, off);
        sq += __shfl_xor(sq, off);
    }
    __shared__ float red[8];
    if ((tid & 63) == 0) { red[tid >> 6] = s; red[4 + (tid >> 6)] = sq; }
    __syncthreads();
    s  = red[0] + red[1] + red[2] + red[3];
    sq = red[4] + red[5] + red[6] + red[7];
    float mu  = s * (1.0f / 1024.0f);
    float var = sq * (1.0f / 1024.0f) - mu * mu;
    float rs  = rsqrtf(var + 1e-5f);
    f32x4 wv = *(const f32x4*)(w + tid * 4);
    f32x4 bv = *(const f32x4*)(b + tid * 4);
    u16x4 o;
    #pragma unroll
    for (int j = 0; j < 4; ++j) o[j] = f2b((v[j] - mu) * rs * wv[j] + bv[j]);
    *(u16x4*)(out + row * 1024 + tid * 4) = o;
}

// ---------------- fused attention: scores + softmax + att-write + PV ----------------
// per block: one (b,h), 128 Q rows. 4 waves in 2x2 grid.
// pass 1: online row max/sum over all 8 key tiles (scores recomputed, not stored)
// pass 2: recompute scores, P = exp(s-m)/l -> att fp32 (global) + P bf16 (LDS) -> PV MFMA
__global__ __launch_bounds__(256)
void attn_fused(const unsigned short* __restrict__ Qg_,   // [64][1024][64], pre-scaled 1/8
                const unsigned short* __restrict__ Kg_,   // [64][1024][64]
                const unsigned short* __restrict__ Vg_,   // [64][64][1024]  (vT)
                const float* __restrict__ mask,           // [1024][1024]
                float* __restrict__ att,                  // [64][1024][1024]
                unsigned short* __restrict__ y)           // [4096][1024] bf16
{
    __shared__ unsigned short Qs[128 * 64];
    __shared__ unsigned short Ks[128 * 64];
    __shared__ unsigned short Vs[64 * 128];
    __shared__ unsigned short Ps[128 * 128];

    const int tid = threadIdx.x, lane = tid & 63, wid = tid >> 6;
    const int wr = wid >> 1, wc = wid & 1;
    const int bh = blockIdx.y;
    const int q0 = blockIdx.x * 128;
    const int fr = lane & 15, fs = lane >> 4;

    const unsigned short* Qg = Qg_ + ((long)bh << 16) + (long)q0 * 64;
    const unsigned short* Kg = Kg_ + ((long)bh << 16);
    const unsigned short* Vg = Vg_ + ((long)bh << 16);

    // ---- stage Q once (swizzled source -> linear LDS dest) ----
    #pragma unroll
    for (int rno = 0; rno < 4; ++rno) {
        int L = rno * 4096 + wid * 1024 + lane * 16;
        int row = L >> 7;
        int w = (L & 127) ^ ((row & 7) << 4);
        gload16(Qg + row * 64 + (w >> 1), &Qs[(rno * 4096 + wid * 1024) >> 1]);
    }
    asm volatile("s_waitcnt vmcnt(0)" ::: "memory");
    __syncthreads();

    float mrun[4][4], lrun[4][4];
    #pragma unroll
    for (int m = 0; m < 4; ++m)
        #pragma unroll
        for (int r = 0; r < 4; ++r) { mrun[m][r] = -1e30f; lrun[m][r] = 0.0f; }

    // ================= pass 1: stats =================
    for (int kt = 0; kt < 8; ++kt) {
        #pragma unroll
        for (int rno = 0; rno < 4; ++rno) {
            int L = rno * 4096 + wid * 1024 + lane * 16;
            int row = L >> 7;
            int w = (L & 127) ^ ((row & 7) << 4);
            gload16(Kg + (long)(kt * 128 + row) * 64 + (w >> 1),
                    &Ks[(rno * 4096 + wid * 1024) >> 1]);
        }
        asm volatile("s_waitcnt vmcnt(0)" ::: "memory");
        __syncthreads();

        f32x4 accs[4][4] = {};
        #pragma unroll
        for (int kk = 0; kk < 2; ++kk) {
            s16x8 af[4], bf[4];
            #pragma unroll
            for (int m = 0; m < 4; ++m) af[m] = rd7(Qs, wr * 64 + m * 16 + fr, kk * 64 + fs * 16);
            #pragma unroll
            for (int n = 0; n < 4; ++n) bf[n] = rd7(Ks, wc * 64 + n * 16 + fr, kk * 64 + fs * 16);
            #pragma unroll
            for (int m = 0; m < 4; ++m)
                #pragma unroll
                for (int n = 0; n < 4; ++n)
                    accs[m][n] = __builtin_amdgcn_mfma_f32_16x16x32_bf16(af[m], bf[n], accs[m][n], 0, 0, 0);
        }

        #pragma unroll
        for (int m = 0; m < 4; ++m) {
            float sv[4][4];
            float tmax[4] = {-1e30f, -1e30f, -1e30f, -1e30f};
            #pragma unroll
            for (int n = 0; n < 4; ++n) {
                const int kcol = kt * 128 + wc * 64 + n * 16 + fr;
                #pragma unroll
                for (int r = 0; r < 4; ++r) {
                    const int qrow = q0 + wr * 64 + m * 16 + fs * 4 + r;
                    float s = accs[m][n][r] + mask[((long)qrow << 10) + kcol];
                    sv[n][r] = s;
                    tmax[r] = fmaxf(tmax[r], s);
                }
            }
            #pragma unroll
            for (int r = 0; r < 4; ++r) {
                float t = tmax[r];
                t = fmaxf(t, __shfl_xor(t, 1)); t = fmaxf(t, __shfl_xor(t, 2));
                t = fmaxf(t, __shfl_xor(t, 4)); t = fmaxf(t, __shfl_xor(t, 8));
                float nm = fmaxf(mrun[m][r], t);
                float ts = __expf(sv[0][r] - nm) + __expf(sv[1][r] - nm)
                         + __expf(sv[2][r] - nm) + __expf(sv[3][r] - nm);
                ts += __shfl_xor(ts, 1); ts += __shfl_xor(ts, 2);
                ts += __shfl_xor(ts, 4); ts += __shfl_xor(ts, 8);
                lrun[m][r] = lrun[m][r] * __expf(mrun[m][r] - nm) + ts;
                mrun[m][r] = nm;
            }
        }
        __syncthreads();
    }

    float invl[4][4];
    #pragma unroll
    for (int m = 0; m < 4; ++m)
        #pragma unroll
        for (int r = 0; r < 4; ++r) invl[m][r] = 1.0f / lrun[m][r];

    f32x4 acco[4][2] = {};

    // ================= pass 2: att write + PV =================
    for (int kt = 0; kt < 8; ++kt) {
        #pragma unroll
        for (int rno = 0; rno < 4; ++rno) {
            int L = rno * 4096 + wid * 1024 + lane * 16;
            int row = L >> 7;
            int w = (L & 127) ^ ((row & 7) << 4);
            gload16(Kg + (long)(kt * 128 + row) * 64 + (w >> 1),
                    &Ks[(rno * 4096 + wid * 1024) >> 1]);
        }
        #pragma unroll
        for (int rno = 0; rno < 4; ++rno) {
            int L = rno * 4096 + wid * 1024 + lane * 16;
            int row = L >> 8;                       // V tile rows are 256B
            int w = (L & 255) ^ ((row & 7) << 4);
            gload16(Vg + (long)row * 1024 + kt * 128 + (w >> 1),
                    &Vs[(rno * 4096 + wid * 1024) >> 1]);
        }
        asm volatile("s_waitcnt vmcnt(0)" ::: "memory");
        __syncthreads();

        f32x4 accs[4][4] = {};
        #pragma unroll
        for (int kk = 0; kk < 2; ++kk) {
            s16x8 af[4], bf[4];
            #pragma unroll
            for (int m = 0; m < 4; ++m) af[m] = rd7(Qs, wr * 64 + m * 16 + fr, kk * 64 + fs * 16);
            #pragma unroll
            for (int n = 0; n < 4; ++n) bf[n] = rd7(Ks, wc * 64 + n * 16 + fr, kk * 64 + fs * 16);
            #pragma unroll
            for (int m = 0; m < 4; ++m)
                #pragma unroll
                for (int n = 0; n < 4; ++n)
                    accs[m][n] = __builtin_amdgcn_mfma_f32_16x16x32_bf16(af[m], bf[n], accs[m][n], 0, 0, 0);
        }

        #pragma unroll
        for (int m = 0; m < 4; ++m) {
            #pragma unroll
            for (int n = 0; n < 4; ++n) {
                const int kcol = kt * 128 + wc * 64 + n * 16 + fr;
                #pragma unroll
                for (int r = 0; r < 4; ++r) {
                    const int qrow = q0 + wr * 64 + m * 16 + fs * 4 + r;
                    float s = accs[m][n][r] + mask[((long)qrow << 10) + kcol];
                    float p = __expf(s - mrun[m][r]) * invl[m][r];
                    att[((long)bh << 20) + ((long)qrow << 10) + kcol] = p;
                    const int prow = wr * 64 + m * 16 + fs * 4 + r;
                    const int pcol = wc * 64 + n * 16 + fr;
                    *(unsigned short*)((char*)Ps + ((prow << 8) + ((pcol * 2) ^ ((prow & 7) << 4)))) = f2b(p);
                }
            }
        }
        __syncthreads();

        #pragma unroll
        for (int kk = 0; kk < 4; ++kk) {
            s16x8 pa[4], vb[2];
            #pragma unroll
            for (int m = 0; m < 4; ++m) pa[m] = rd8(Ps, wr * 64 + m * 16 + fr, kk * 64 + fs * 16);
            #pragma unroll
            for (int n = 0; n < 2; ++n) vb[n] = rd8(Vs, wc * 32 + n * 16 + fr, kk * 64 + fs * 16);
            #pragma unroll
            for (int m = 0; m < 4; ++m)
                #pragma unroll
                for (int n = 0; n < 2; ++n)
                    acco[m][n] = __builtin_amdgcn_mfma_f32_16x16x32_bf16(pa[m], vb[n], acco[m][n], 0, 0, 0);
        }
        __syncthreads();
    }

    // ---- write y [B,T,C] bf16 ----
    const int bb = bh >> 4, hh = bh & 15;
    #pragma unroll
    for (int m = 0; m < 4; ++m) {
        #pragma unroll
        for (int n = 0; n < 2; ++n) {
            #pragma unroll
            for (int r = 0; r < 4; ++r) {
                const int t = q0 + wr * 64 + m * 16 + fs * 4 + r;
                const int c = hh * 64 + wc * 32 + n * 16 + fr;
                y[((long)(bb * 1024 + t) << 10) + c] = f2b(acco[m][n][r]);
            }
        }
    }
}

// ---------------- GEMM: C[n,m] = sum_k A[n,k] * B[m,k]  (both row-major over K) --------
// EPI: 0=QKV scatter, 3=bias+resid->f32, 4=bias+GELU->bf16, 5=bias+resid->f32
template <int BM, int BN, int EPI>
__global__ __launch_bounds__(256)
void gemm_bt(const unsigned short* __restrict__ A,
             const unsigned short* __restrict__ Bm,
             int K, int lda, int ldb, int ldc,
             const float* __restrict__ bias,
             const float* __restrict__ resid,
             float* __restrict__ outF,
             unsigned short* __restrict__ outB) {
    constexpr int WM = BM / 2, WN = BN / 2;
    constexpr int FM = WM / 16, FN = WN / 16;
    __shared__ unsigned short ldsA[BM * 32];
    __shared__ unsigned short ldsB[BN * 32];

    const int tid  = threadIdx.x;
    const int lane = tid & 63;
    const int wid  = tid >> 6;
    const int wr   = wid >> 1, wc = wid & 1;
    const int row0 = blockIdx.x * BM;
    const int col0 = blockIdx.y * BN;

    const unsigned short* Ab = A + (long)row0 * lda;
    const unsigned short* Bb = Bm + (long)col0 * ldb;

    f32x4 acc[FM][FN] = {};
    const int fr = lane & 15;
    const int fk = (lane >> 4) * 8;

    for (int k0 = 0; k0 < K; k0 += 32) {
        #pragma unroll
        for (int i = 0; i < BM / 64; ++i) {
            int e = i * 2048 + wid * 512 + lane * 8;
            gload16(Ab + k0 + (long)(e >> 5) * lda + (e & 31),
                    &ldsA[i * 2048 + wid * 512]);
        }
        #pragma unroll
        for (int i = 0; i < BN / 64; ++i) {
            int e = i * 2048 + wid * 512 + lane * 8;
            gload16(Bb + k0 + (long)(e >> 5) * ldb + (e & 31),
                    &ldsB[i * 2048 + wid * 512]);
        }
        asm volatile("s_waitcnt vmcnt(0)" ::: "memory");
        __syncthreads();

        s16x8 af[FM], bfr[FN];
        #pragma unroll
        for (int m = 0; m < FM; ++m)
            af[m] = *(const s16x8*)&ldsA[(wr * WM + m * 16 + fr) * 32 + fk];
        #pragma unroll
        for (int n = 0; n < FN; ++n)
            bfr[n] = *(const s16x8*)&ldsB[(wc * WN + n * 16 + fr) * 32 + fk];
        #pragma unroll
        for (int m = 0; m < FM; ++m)
            #pragma unroll
            for (int n = 0; n < FN; ++n)
                acc[m][n] = __builtin_amdgcn_mfma_f32_16x16x32_bf16(af[m], bfr[n], acc[m][n], 0, 0, 0);
        __syncthreads();
    }

    const int cj = lane & 15;
    const int r0 = (lane >> 4) * 4;
    #pragma unroll
    for (int m = 0; m < FM; ++m) {
        #pragma unroll
        for (int n = 0; n < FN; ++n) {
            #pragma unroll
            for (int r = 0; r < 4; ++r) {
                const int grow = row0 + wr * WM + m * 16 + r0 + r;
                const int gcol = col0 + wc * WN + n * 16 + cj;
                float v = acc[m][n][r];
                if constexpr (EPI == 0) {
                    v += bias[gcol];
                    const int bb = grow >> 10, t = grow & 1023;
                    const int seg = gcol >> 10, mm = gcol & 1023;
                    const int hh = mm >> 6, dd = mm & 63;
                    const long bh = bb * 16 + hh;
                    if (seg == 0)
                        outB[(bh << 16) + (t << 6) + dd] = f2b(v * 0.125f);
                    else if (seg == 1)
                        outB[4194304 + (bh << 16) + (t << 6) + dd] = f2b(v);
                    else
                        outB[8388608 + (bh << 16) + (dd << 10) + t] = f2b(v);
                } else if constexpr (EPI == 3 || EPI == 5) {
                    const long idx = ((long)grow << 10) + gcol;   // ldc = 1024
                    outF[idx] = v + bias[gcol] + resid[idx];
                } else if constexpr (EPI == 4) {
                    float u = v + bias[gcol];
                    float g = 0.5f * u * (1.0f + erff(u * 0.70710678118f));
                    outB[(long)grow * ldc + gcol] = f2b(g);
                }
            }
        }
    }
}

// ---------------- launch ----------------
extern "C" void kernel_launch(void* const* d_in, const int* in_sizes, int n_in,
                              void* d_out, int out_size, void* d_ws, size_t ws_size,
                              hipStream_t stream) {
    (void)in_sizes; (void)n_in; (void)out_size; (void)ws_size;
    const float* x     = (const float*)d_in[0];
    const float* mask  = (const float*)d_in[1];
    const float* ln1w  = (const float*)d_in[2];
    const float* ln1b  = (const float*)d_in[3];
    const float* wqkv  = (const float*)d_in[4];
    const float* bqkv  = (const float*)d_in[5];
    const float* wo    = (const float*)d_in[6];
    const float* bo    = (const float*)d_in[7];
    const float* ln2w  = (const float*)d_in[8];
    const float* ln2b  = (const float*)d_in[9];
    const float* wfc   = (const float*)d_in[10];
    const float* bfc   = (const float*)d_in[11];
    const float* wproj = (const float*)d_in[12];
    const float* bproj = (const float*)d_in[13];

    float* outx = (float*)d_out;                     // [4096,1024] fp32
    float* att  = (float*)d_out + 4194304;           // [64,1024,1024] fp32

    char* ws = (char*)d_ws;
    unsigned short* h_bf     = (unsigned short*)ws;  ws += (size_t)8  << 20;  // [4096,1024]
    unsigned short* wqkv_bf  = (unsigned short*)ws;  ws += (size_t)6  << 20;  // [3072,1024]
    unsigned short* wo_bf    = (unsigned short*)ws;  ws += (size_t)2  << 20;  // [1024,1024]
    unsigned short* wfc_bf   = (unsigned short*)ws;  ws += (size_t)8  << 20;  // [4096,1024]
    unsigned short* wproj_bf = (unsigned short*)ws;  ws += (size_t)8  << 20;  // [1024,4096]
    unsigned short* q_bf     = (unsigned short*)ws;  ws += (size_t)24 << 20;  // q,k,vT contiguous
    unsigned short* k_bf     = q_bf + 4194304;
    unsigned short* vT_bf    = q_bf + 8388608;
    unsigned short* y_bf     = (unsigned short*)ws;  ws += (size_t)8  << 20;  // [4096,1024]
    float*          x2       = (float*)ws;           ws += (size_t)16 << 20;  // [4096,1024] f32
    unsigned short* gelu_bf  = (unsigned short*)ws;  ws += (size_t)32 << 20;  // [4096,4096]

    // weights -> bf16
    cast_kernel<<<3072, 256, 0, stream>>>(wqkv,  wqkv_bf,  786432);
    cast_kernel<<<1024, 256, 0, stream>>>(wo,    wo_bf,    262144);
    cast_kernel<<<4096, 256, 0, stream>>>(wfc,   wfc_bf,   1048576);
    cast_kernel<<<4096, 256, 0, stream>>>(wproj, wproj_bf, 1048576);

    // LN1
    ln_kernel<<<4096, 256, 0, stream>>>(x, ln1w, ln1b, h_bf);

    // QKV: [4096,1024] x [3072,1024]^T  -> q(scaled)/k/vT scatter
    gemm_bt<128, 128, 0><<<dim3(32, 24, 1), 256, 0, stream>>>(
        h_bf, wqkv_bf, 1024, 1024, 1024, 0,
        bqkv, nullptr, nullptr, q_bf);

    // fused attention: scores + softmax + att fp32 + PV -> y_bf
    attn_fused<<<dim3(8, 64), 256, 0, stream>>>(
        q_bf, k_bf, vT_bf, mask, att, y_bf);

    // W_o: [4096,1024] x [1024,1024]^T + b_o + x -> x2
    gemm_bt<128, 128, 3><<<dim3(32, 8, 1), 256, 0, stream>>>(
        y_bf, wo_bf, 1024, 1024, 1024, 1024,
        bo, x, x2, nullptr);

    // LN2
    ln_kernel<<<4096, 256, 0, stream>>>(x2, ln2w, ln2b, h_bf);

    // FC + GELU: [4096,1024] x [4096,1024]^T -> gelu_bf [4096,4096]
    gemm_bt<128, 128, 4><<<dim3(32, 32, 1), 256, 0, stream>>>(
        h_bf, wfc_bf, 1024, 1024, 1024, 4096,
        bfc, nullptr, nullptr, gelu_bf);

    // Proj: [4096,4096] x [1024,4096]^T + b_proj + x2 -> out
    gemm_bt<128, 128, 5><<<dim3(32, 8, 1), 256, 0, stream>>>(
        gelu_bf, wproj_bf, 4096, 4096, 4096, 1024,
        bproj, x2, outx, nullptr);
}

// Round 3
// 454.277 us; speedup vs baseline: 1.4366x; 1.4366x over previous
//
#include <hip/hip_runtime.h>
#include <hip/hip_fp16.h>
#include <stdint.h>
#include <math.h>

// ---------------- types ----------------
typedef __attribute__((ext_vector_type(4))) float f32x4;
typedef __attribute__((ext_vector_type(8))) short s16x8;   // 8 x bf16 (4 VGPRs)
typedef __attribute__((ext_vector_type(4))) unsigned short u16x4;

__device__ __forceinline__ unsigned short f2b(float x) {
    union { float f; uint32_t u; } v; v.f = x;
    uint32_t r = v.u + 0x7FFFu + ((v.u >> 16) & 1u);   // round-to-nearest-even
    return (unsigned short)(r >> 16);
}

__device__ __forceinline__ unsigned short f2h(float x) {
    __half h = __float2half(x);
    return *(unsigned short*)&h;
}
__device__ __forceinline__ float h2f(unsigned short u) {
    __half h = *(__half*)&u;
    return __half2float(h);
}

__device__ __forceinline__ void gload16(const unsigned short* g, unsigned short* l) {
    __builtin_amdgcn_global_load_lds(
        (const __attribute__((address_space(1))) unsigned int*)(const void*)g,
        (__attribute__((address_space(3))) unsigned int*)(void*)l,
        16, 0, 0);
}

// ---------------- fused fp32 -> bf16 cast of the 4 weight tensors ----------------
__global__ __launch_bounds__(256) void cast4_kernel(
        const float* __restrict__ a, int na, const float* __restrict__ b, int nb,
        const float* __restrict__ c, int nc, const float* __restrict__ d, int nd,
        unsigned short* __restrict__ oa, unsigned short* __restrict__ ob,
        unsigned short* __restrict__ oc, unsigned short* __restrict__ od) {
    int i = blockIdx.x * 256 + threadIdx.x;
    const float* src; unsigned short* dst; int off;
    if (i < na)                { src = a; dst = oa; off = i; }
    else if (i < na+nb)        { src = b; dst = ob; off = i - na; }
    else if (i < na+nb+nc)     { src = c; dst = oc; off = i - na - nb; }
    else if (i < na+nb+nc+nd)  { src = d; dst = od; off = i - na - nb - nc; }
    else return;
    f32x4 v = ((const f32x4*)src)[off];
    u16x4 o;
    #pragma unroll
    for (int j = 0; j < 4; ++j) o[j] = f2b(v[j]);
    ((u16x4*)dst)[off] = o;
}

// ---------------- LayerNorm (C=1024), fp32 in -> bf16 out ----------------
__global__ __launch_bounds__(256) void ln_kernel(const float* __restrict__ x,
                                                 const float* __restrict__ w,
                                                 const float* __restrict__ b,
                                                 unsigned short* __restrict__ out) {
    const long row = blockIdx.x;
    const int tid = threadIdx.x;
    f32x4 v = *(const f32x4*)(x + row * 1024 + tid * 4);
    float s  = v[0] + v[1] + v[2] + v[3];
    float sq = v[0]*v[0] + v[1]*v[1] + v[2]*v[2] + v[3]*v[3];
    #pragma unroll
    for (int off = 32; off; off >>= 1) {
        s  += __shfl_xor(s, off);
        sq += __shfl_xor(sq, off);
    }
    __shared__ float red[8];
    if ((tid & 63) == 0) { red[tid >> 6] = s; red[4 + (tid >> 6)] = sq; }
    __syncthreads();
    s  = red[0] + red[1] + red[2] + red[3];
    sq = red[4] + red[5] + red[6] + red[7];
    float mu  = s * (1.0f / 1024.0f);
    float var = sq * (1.0f / 1024.0f) - mu * mu;
    float rs  = rsqrtf(var + 1e-5f);
    f32x4 wv = *(const f32x4*)(w + tid * 4);
    f32x4 bv = *(const f32x4*)(b + tid * 4);
    u16x4 o;
    #pragma unroll
    for (int j = 0; j < 4; ++j) o[j] = f2b((v[j] - mu) * rs * wv[j] + bv[j]);
    *(u16x4*)(out + row * 1024 + tid * 4) = o;
}

// ---------------- row softmax: fp16 raw s (+mask) -> att fp32 + bf16 P in place ----------
__global__ __launch_bounds__(256) void softmax_kernel(unsigned short* __restrict__ sh,
                                                      const float* __restrict__ mask,
                                                      float* __restrict__ att) {
    const long row = blockIdx.x;            // bh*1024 + t
    const int t = blockIdx.x & 1023;
    const int tid = threadIdx.x;
    u16x4 raw = *(const u16x4*)(sh + row * 1024 + tid * 4);
    f32x4 mv = *(const f32x4*)(mask + (long)t * 1024 + tid * 4);
    float v[4];
    #pragma unroll
    for (int j = 0; j < 4; ++j) v[j] = h2f(raw[j]) + mv[j];
    float mx = fmaxf(fmaxf(v[0], v[1]), fmaxf(v[2], v[3]));
    #pragma unroll
    for (int off = 32; off; off >>= 1) mx = fmaxf(mx, __shfl_xor(mx, off));
    __shared__ float red[8];
    if ((tid & 63) == 0) red[tid >> 6] = mx;
    __syncthreads();
    mx = fmaxf(fmaxf(red[0], red[1]), fmaxf(red[2], red[3]));
    float s = 0.0f;
    #pragma unroll
    for (int j = 0; j < 4; ++j) { v[j] = __expf(v[j] - mx); s += v[j]; }
    #pragma unroll
    for (int off = 32; off; off >>= 1) s += __shfl_xor(s, off);
    if ((tid & 63) == 0) red[4 + (tid >> 6)] = s;
    __syncthreads();
    s = red[4] + red[5] + red[6] + red[7];
    float inv = 1.0f / s;
    f32x4 o; u16x4 ob;
    #pragma unroll
    for (int j = 0; j < 4; ++j) { o[j] = v[j] * inv; ob[j] = f2b(o[j]); }
    *(f32x4*)(att + row * 1024 + tid * 4) = o;      // normalized fp32 att (output 1)
    *(u16x4*)(sh + row * 1024 + tid * 4) = ob;      // bf16 P for PV, in place
}

// ---------------- GEMM: C[n,m] = sum_k A[n,k] * B[m,k]  (both row-major over K) --------
// EPI: 0=QKV scatter, 1=raw scores->fp16, 2=PV scatter->y bf16,
//      3=bias+resid->f32, 4=bias+GELU->bf16
template <int BM, int BN, int EPI>
__global__ __launch_bounds__(256)
void gemm_bt(const unsigned short* __restrict__ A,
             const unsigned short* __restrict__ Bm,
             int K, int lda, int ldb, int ldc,
             long sAz, long sBz,
             const float* __restrict__ bias,
             const float* __restrict__ resid,
             float* __restrict__ outF,
             unsigned short* __restrict__ outB) {
    constexpr int WM = BM / 2, WN = BN / 2;
    constexpr int FM = WM / 16, FN = WN / 16;
    __shared__ unsigned short ldsA[BM * 32];
    __shared__ unsigned short ldsB[BN * 32];

    const int tid  = threadIdx.x;
    const int lane = tid & 63;
    const int wid  = tid >> 6;
    const int wr   = wid >> 1, wc = wid & 1;
    const int bz   = blockIdx.z;
    const int row0 = blockIdx.x * BM;
    const int col0 = blockIdx.y * BN;

    const unsigned short* Ab = A + (long)bz * sAz + (long)row0 * lda;
    const unsigned short* Bb = Bm + (long)bz * sBz + (long)col0 * ldb;

    f32x4 acc[FM][FN] = {};
    const int fr = lane & 15;
    const int fk = (lane >> 4) * 8;

    for (int k0 = 0; k0 < K; k0 += 32) {
        #pragma unroll
        for (int i = 0; i < BM / 64; ++i) {
            int e = i * 2048 + wid * 512 + lane * 8;
            gload16(Ab + k0 + (long)(e >> 5) * lda + (e & 31),
                    &ldsA[i * 2048 + wid * 512]);
        }
        #pragma unroll
        for (int i = 0; i < BN / 64; ++i) {
            int e = i * 2048 + wid * 512 + lane * 8;
            gload16(Bb + k0 + (long)(e >> 5) * ldb + (e & 31),
                    &ldsB[i * 2048 + wid * 512]);
        }
        asm volatile("s_waitcnt vmcnt(0)" ::: "memory");
        __syncthreads();

        s16x8 af[FM], bfr[FN];
        #pragma unroll
        for (int m = 0; m < FM; ++m)
            af[m] = *(const s16x8*)&ldsA[(wr * WM + m * 16 + fr) * 32 + fk];
        #pragma unroll
        for (int n = 0; n < FN; ++n)
            bfr[n] = *(const s16x8*)&ldsB[(wc * WN + n * 16 + fr) * 32 + fk];
        #pragma unroll
        for (int m = 0; m < FM; ++m)
            #pragma unroll
            for (int n = 0; n < FN; ++n)
                acc[m][n] = __builtin_amdgcn_mfma_f32_16x16x32_bf16(af[m], bfr[n], acc[m][n], 0, 0, 0);
        __syncthreads();
    }

    // epilogue: D mapping col=lane&15, row=(lane>>4)*4+reg  [m89-verified]
    const int cj = lane & 15;
    const int r0 = (lane >> 4) * 4;
    #pragma unroll
    for (int m = 0; m < FM; ++m) {
        #pragma unroll
        for (int n = 0; n < FN; ++n) {
            #pragma unroll
            for (int r = 0; r < 4; ++r) {
                const int grow = row0 + wr * WM + m * 16 + r0 + r;
                const int gcol = col0 + wc * WN + n * 16 + cj;
                float v = acc[m][n][r];
                if constexpr (EPI == 0) {
                    // QKV scatter: q scaled 1/8 -> [BH,T,64]; k -> [BH,T,64]; v -> vT [BH,64,T]
                    v += bias[gcol];
                    const int bb = grow >> 10, t = grow & 1023;
                    const int seg = gcol >> 10, mm = gcol & 1023;
                    const int hh = mm >> 6, dd = mm & 63;
                    const long bh = bb * 16 + hh;
                    if (seg == 0)
                        outB[(bh << 16) + (t << 6) + dd] = f2b(v * 0.125f);
                    else if (seg == 1)
                        outB[4194304 + (bh << 16) + (t << 6) + dd] = f2b(v);
                    else
                        outB[8388608 + (bh << 16) + (dd << 10) + t] = f2b(v);
                } else if constexpr (EPI == 1) {
                    outB[((long)bz << 20) + ((long)grow << 10) + gcol] = f2h(v);
                } else if constexpr (EPI == 2) {
                    const int bb = bz >> 4, hh = bz & 15;
                    outB[((long)((bb << 10) | grow) << 10) + (hh << 6) + gcol] = f2b(v);
                } else if constexpr (EPI == 3) {
                    const long idx = ((long)grow << 10) + gcol;   // out row stride 1024
                    outF[idx] = v + bias[gcol] + resid[idx];
                } else if constexpr (EPI == 4) {
                    float u = v + bias[gcol];
                    float g = 0.5f * u * (1.0f + erff(u * 0.70710678118f));
                    outB[(long)grow * ldc + gcol] = f2b(g);
                }
            }
        }
    }
}

// ---------------- launch ----------------
extern "C" void kernel_launch(void* const* d_in, const int* in_sizes, int n_in,
                              void* d_out, int out_size, void* d_ws, size_t ws_size,
                              hipStream_t stream) {
    (void)in_sizes; (void)n_in; (void)out_size; (void)ws_size;
    const float* x     = (const float*)d_in[0];
    const float* mask  = (const float*)d_in[1];
    const float* ln1w  = (const float*)d_in[2];
    const float* ln1b  = (const float*)d_in[3];
    const float* wqkv  = (const float*)d_in[4];
    const float* bqkv  = (const float*)d_in[5];
    const float* wo    = (const float*)d_in[6];
    const float* bo    = (const float*)d_in[7];
    const float* ln2w  = (const float*)d_in[8];
    const float* ln2b  = (const float*)d_in[9];
    const float* wfc   = (const float*)d_in[10];
    const float* bfc   = (const float*)d_in[11];
    const float* wproj = (const float*)d_in[12];
    const float* bproj = (const float*)d_in[13];

    float* outx = (float*)d_out;                     // [4096,1024] fp32
    float* att  = (float*)d_out + 4194304;           // [64,1024,1024] fp32

    char* ws = (char*)d_ws;
    unsigned short* h_bf     = (unsigned short*)ws;  ws += (size_t)8  << 20;  // [4096,1024]
    unsigned short* wqkv_bf  = (unsigned short*)ws;  ws += (size_t)6  << 20;  // [3072,1024]
    unsigned short* wo_bf    = (unsigned short*)ws;  ws += (size_t)2  << 20;  // [1024,1024]
    unsigned short* wfc_bf   = (unsigned short*)ws;  ws += (size_t)8  << 20;  // [4096,1024]
    unsigned short* wproj_bf = (unsigned short*)ws;  ws += (size_t)8  << 20;  // [1024,4096]
    unsigned short* q_bf     = (unsigned short*)ws;  ws += (size_t)24 << 20;  // q,k,vT contiguous
    unsigned short* k_bf     = q_bf + 4194304;
    unsigned short* vT_bf    = q_bf + 8388608;
    unsigned short* s_h      = (unsigned short*)ws;  ws += (size_t)128 << 20; // [64,1024,1024] fp16 -> bf16 P
    unsigned short* y_bf     = (unsigned short*)ws;  ws += (size_t)8  << 20;  // [4096,1024]
    float*          x2       = (float*)ws;           ws += (size_t)16 << 20;  // [4096,1024] f32
    unsigned short* gelu_bf  = (unsigned short*)ws;  ws += (size_t)32 << 20;  // [4096,4096]

    // weights -> bf16 (single fused launch)
    cast4_kernel<<<12288, 256, 0, stream>>>(
        wqkv, 786432, wo, 262144, wfc, 1048576, wproj, 1048576,
        wqkv_bf, wo_bf, wfc_bf, wproj_bf);

    // LN1
    ln_kernel<<<4096, 256, 0, stream>>>(x, ln1w, ln1b, h_bf);

    // QKV: [4096,1024] x [3072,1024]^T -> q(scaled)/k/vT scatter
    gemm_bt<128, 128, 0><<<dim3(32, 24, 1), 256, 0, stream>>>(
        h_bf, wqkv_bf, 1024, 1024, 1024, 0, 0, 0,
        bqkv, nullptr, nullptr, q_bf);

    // scores: per (b,h): [1024,64] x [1024,64]^T -> raw fp16 s
    gemm_bt<128, 128, 1><<<dim3(8, 8, 64), 256, 0, stream>>>(
        q_bf, k_bf, 64, 64, 64, 0, 65536, 65536,
        nullptr, nullptr, nullptr, s_h);

    // softmax rows: fp16 s + mask -> att fp32 + bf16 P (in place)
    softmax_kernel<<<65536, 256, 0, stream>>>(s_h, mask, att);

    // PV: per (b,h): [1024,1024] x [64,1024]^T -> y [B,T,C]
    gemm_bt<128, 64, 2><<<dim3(8, 1, 64), 256, 0, stream>>>(
        s_h, vT_bf, 1024, 1024, 1024, 0, 1048576, 65536,
        nullptr, nullptr, nullptr, y_bf);

    // W_o: [4096,1024] x [1024,1024]^T + b_o + x -> x2
    gemm_bt<64, 128, 3><<<dim3(64, 8, 1), 256, 0, stream>>>(
        y_bf, wo_bf, 1024, 1024, 1024, 1024, 0, 0,
        bo, x, x2, nullptr);

    // LN2
    ln_kernel<<<4096, 256, 0, stream>>>(x2, ln2w, ln2b, h_bf);

    // FC + GELU: [4096,1024] x [4096,1024]^T -> gelu_bf [4096,4096]
    gemm_bt<128, 128, 4><<<dim3(32, 32, 1), 256, 0, stream>>>(
        h_bf, wfc_bf, 1024, 1024, 1024, 4096, 0, 0,
        bfc, nullptr, nullptr, gelu_bf);

    // Proj: [4096,4096] x [1024,4096]^T + b_proj + x2 -> out
    gemm_bt<64, 128, 3><<<dim3(64, 8, 1), 256, 0, stream>>>(
        gelu_bf, wproj_bf, 4096, 4096, 4096, 1024, 0, 0,
        bproj, x2, outx, nullptr);
}